// Round 1
// 3504.651 us; speedup vs baseline: 2.2189x; 2.2189x over previous
//
#include <hip/hip_runtime.h>
#include <math.h>

// Problem constants
#define BATCH 4
#define TSEQ  4096
#define CEMB  2048
#define NHEAD 16
#define NSEG  8
#define SEGL  512     // L: rows per (b,h,s) tile
#define DHEAD 128
#define BT    16384   // BATCH*TSEQ
#define NTILE 512     // BATCH*NHEAD*NSEG

// tile index decode: tile = ((b*16+h)*8+s)
// row l of tile -> t = h*256 + s*32 + (l>>4); col base = (l&15)*128

typedef unsigned short bf16;
typedef __attribute__((ext_vector_type(8))) short bf16x8;  // 8 bf16 = 4 VGPRs
typedef __attribute__((ext_vector_type(4))) float f32x4;

__device__ __forceinline__ float elup1p(float x) {
    return x > 0.0f ? x + 1.0f : expf(x);
}
__device__ __forceinline__ float bf2f(bf16 u) {
    return __uint_as_float(((unsigned int)u) << 16);
}
__device__ __forceinline__ bf16 f2bf(float f) {
    unsigned int x = __float_as_uint(f);
    return (bf16)((x + 0x7fffu + ((x >> 16) & 1u)) >> 16);
}
__device__ __forceinline__ void ld4(const float* p, float f[4]) {
    float4 v = *(const float4*)p;
    f[0] = v.x; f[1] = v.y; f[2] = v.z; f[3] = v.w;
}
__device__ __forceinline__ void ld4(const bf16* p, float f[4]) {
    ushort4 v = *(const ushort4*)p;
    f[0] = bf2f(v.x); f[1] = bf2f(v.y); f[2] = bf2f(v.z); f[3] = bf2f(v.w);
}
__device__ __forceinline__ void st4(float* p, const float f[4]) {
    *(float4*)p = make_float4(f[0], f[1], f[2], f[3]);
}
__device__ __forceinline__ void st4(bf16* p, const float f[4]) {
    ushort4 v;
    v.x = f2bf(f[0]); v.y = f2bf(f[1]); v.z = f2bf(f[2]); v.w = f2bf(f[3]);
    *(ushort4*)p = v;
}

// async global->LDS, 16B per lane (CK-style address-space casts).
// LDS dest is wave-uniform base + lane*16 (HW semantics).
__device__ __forceinline__ void gload16(const void* g, void* l) {
    typedef __attribute__((address_space(1))) const char GC;
    typedef __attribute__((address_space(3))) char LC;
    GC* gp = reinterpret_cast<GC*>((unsigned long long)g);
    LC* lp = reinterpret_cast<LC*>((unsigned int)(unsigned long long)l);
    __builtin_amdgcn_global_load_lds(gp, lp, 16, 0, 0);
}

// ---------------------------------------------------------------------------
// Split fp32 -> bf16 hi/lo:  x ~= hi + lo,  |x - hi - lo| <~ 2^-18 |x|
// ---------------------------------------------------------------------------
__global__ __launch_bounds__(256) void split_x_kernel(
    const float* __restrict__ X, bf16* __restrict__ Xh, bf16* __restrict__ Xl) {
    const size_t i4 = ((size_t)blockIdx.x * 256 + threadIdx.x) * 4;
    const float4 v = *(const float4*)&X[i4];
    float f[4] = {v.x, v.y, v.z, v.w};
    ushort4 h, l;
    unsigned short* hp = &h.x;
    unsigned short* lp = &l.x;
#pragma unroll
    for (int q = 0; q < 4; ++q) {
        bf16 hi = f2bf(f[q]);
        hp[q] = hi;
        lp[q] = f2bf(f[q] - bf2f(hi));
    }
    *(ushort4*)&Xh[i4] = h;
    *(ushort4*)&Xl[i4] = l;
}

// Split + transpose W[K][N] fp32 -> WhT/WlT[N][K] bf16 (64x64 tiles).
__global__ __launch_bounds__(256) void split_wT_kernel(
    const float* __restrict__ W, bf16* __restrict__ WhT, bf16* __restrict__ WlT) {
    __shared__ float T[64][65];
    const int k0 = blockIdx.x * 64;
    const int n0 = blockIdx.y * 64;
    const int tid = threadIdx.x;
    const int tr = tid >> 4;
    const int tc4 = (tid & 15) * 4;
#pragma unroll
    for (int rr = 0; rr < 4; ++rr) {
        const int kr = rr * 16 + tr;
        const float4 v = *(const float4*)&W[(size_t)(k0 + kr) * CEMB + n0 + tc4];
        T[kr][tc4 + 0] = v.x; T[kr][tc4 + 1] = v.y;
        T[kr][tc4 + 2] = v.z; T[kr][tc4 + 3] = v.w;
    }
    __syncthreads();
#pragma unroll
    for (int rr = 0; rr < 4; ++rr) {
        const int nr = rr * 16 + tr;
        ushort4 h, l;
        unsigned short* hp = &h.x;
        unsigned short* lp = &l.x;
#pragma unroll
        for (int q = 0; q < 4; ++q) {
            float f = T[tc4 + q][nr];
            bf16 hi = f2bf(f);
            hp[q] = hi;
            lp[q] = f2bf(f - bf2f(hi));
        }
        *(ushort4*)&WhT[(size_t)(n0 + nr) * CEMB + k0 + tc4] = h;
        *(ushort4*)&WlT[(size_t)(n0 + nr) * CEMB + k0 + tc4] = l;
    }
}

// RoPE cos/sin table: tab[t*1024 + p] = (cos, sin)(t * invf[p]).
// Same math as the previously-verified epilogue: fp32 angle, f64 sincos.
__global__ __launch_bounds__(256) void rope_table_kernel(float2* __restrict__ tab) {
    const int idx = blockIdx.x * 256 + threadIdx.x;
    const int t = idx >> 10, p = idx & 1023;
    const double kfreq = -0.0089944730195079925;  // -ln(10000)/1024
    const float invf = (float)exp((double)p * kfreq);
    const float ang = (float)t * invf;             // fp32 mult mimics reference outer()
    double sd, cd;
    sincos((double)ang, &sd, &cd);
    tab[idx] = make_float2((float)cd, (float)sd);
}

// ---------------------------------------------------------------------------
// MFMA GEMM: Y[M,N] = sum_ph A_ph[M,K] @ B_ph[N,K]^T + bias, optional RoPE.
// A row-major [M,K] bf16; B given TRANSPOSED [N,K] bf16 (so both operand
// fragments read 8 contiguous k).  Split-precision: NPH phases accumulate
// into the same fp32 acc (Ah@Bh + Al@Bh + Ah@Bl ~= fp32 GEMM).
// 128x128 tile, 4 waves (2x2), 16x16x32 MFMA, 4x4 frags/wave, BK=64,
// single LDS buffer + 2 barriers/K-step (m97 structure).
// LDS k-slot XOR swizzle (slot ^= row&7) applied on BOTH the pre-swizzled
// global source and the ds_read -> frag reads are 2-way (free) not 16-way.
// ---------------------------------------------------------------------------
template <typename TOUT, bool ROPE, int NPH>
__global__ __launch_bounds__(256) void gemm_mfma(
    const bf16* __restrict__ A0, const bf16* __restrict__ A1, const bf16* __restrict__ A2,
    const bf16* __restrict__ B0, const bf16* __restrict__ B1, const bf16* __restrict__ B2,
    const float* __restrict__ bias, const float2* __restrict__ rtab,
    TOUT* __restrict__ Y) {
    __shared__ alignas(16) bf16 Asb[128 * 64];
    __shared__ alignas(16) bf16 Bsb[128 * 64];
    const int tid = threadIdx.x;
    const int lane = tid & 63;
    const int wid = __builtin_amdgcn_readfirstlane(tid >> 6);
    const int wr = wid >> 1, wc = wid & 1;
    const int n0 = blockIdx.x * 128;
    const int m0 = blockIdx.y * 128;

    f32x4 acc[4][4];
#pragma unroll
    for (int i = 0; i < 4; ++i)
#pragma unroll
        for (int j = 0; j < 4; ++j) acc[i][j] = (f32x4){0.f, 0.f, 0.f, 0.f};

    // staging: inst (wave,i) covers 8 rows x 64 k; lane l -> row +(l>>3),
    // 16B k-chunk at swizzled slot (l&7)^(l>>3) of that row.
    const int soct = lane >> 3;
    const int sslot = (lane & 7) ^ soct;
    const size_t arow = (size_t)(m0 + wid * 32 + soct);
    const size_t brow = (size_t)(n0 + wid * 32 + soct);

    const int frow_a0 = wr * 64 + (lane & 15);
    const int frow_b0 = wc * 64 + (lane & 15);
    const int fk = lane >> 4;  // 16B-slot index within kk half

    for (int ph = 0; ph < NPH; ++ph) {
        const bf16* Ap = (ph == 0) ? A0 : ((ph == 1) ? A1 : A2);
        const bf16* Bp = (ph == 0) ? B0 : ((ph == 1) ? B1 : B2);
        const bf16* ga = Ap + arow * CEMB + sslot * 8;
        const bf16* gb = Bp + brow * CEMB + sslot * 8;
        for (int k0 = 0; k0 < CEMB; k0 += 64) {
            __syncthreads();  // previous tile's compute done before overwrite
#pragma unroll
            for (int i = 0; i < 4; ++i)
                gload16(ga + (size_t)i * 8 * CEMB, &Asb[(wid * 32 + i * 8) * 64]);
#pragma unroll
            for (int i = 0; i < 4; ++i)
                gload16(gb + (size_t)i * 8 * CEMB, &Bsb[(wid * 32 + i * 8) * 64]);
            ga += 64; gb += 64;
            __syncthreads();  // compiler drains vmcnt(0) before this barrier
#pragma unroll
            for (int kk = 0; kk < 2; ++kk) {
                bf16x8 af[4], bfr[4];
#pragma unroll
                for (int i = 0; i < 4; ++i) {
                    const int r = frow_a0 + i * 16;
                    const int slot = (kk * 4 + fk) ^ (r & 7);
                    af[i] = *(const bf16x8*)((const char*)Asb + r * 128 + slot * 16);
                }
#pragma unroll
                for (int j = 0; j < 4; ++j) {
                    const int r = frow_b0 + j * 16;
                    const int slot = (kk * 4 + fk) ^ (r & 7);
                    bfr[j] = *(const bf16x8*)((const char*)Bsb + r * 128 + slot * 16);
                }
#pragma unroll
                for (int i = 0; i < 4; ++i)
#pragma unroll
                    for (int j = 0; j < 4; ++j)
                        acc[i][j] = __builtin_amdgcn_mfma_f32_16x16x32_bf16(
                            af[i], bfr[j], acc[i][j], 0, 0, 0);
            }
        }
    }

    // epilogue: C/D layout col=lane&15, row=(lane>>4)*4+reg (HW-verified).
    const int gc0 = n0 + wc * 64 + (lane & 15);
    const int gr0 = m0 + wr * 64 + (lane >> 4) * 4;
#pragma unroll
    for (int j = 0; j < 4; ++j) {
        const int c = gc0 + j * 16;
        const float bs = bias[c];
        const int p = c >> 1;
#pragma unroll
        for (int i = 0; i < 4; ++i) {
#pragma unroll
            for (int r = 0; r < 4; ++r) {
                const int row = gr0 + i * 16 + r;
                float v = acc[i][j][r] + bs;
                if (ROPE) {
                    // channel pair (2p,2p+1) sits in lanes (l, l^1)
                    const float2 cs = rtab[(size_t)(row & (TSEQ - 1)) * (CEMB / 2) + p];
                    const float o = __shfl_xor(v, 1, 64);
                    v = ((lane & 1) == 0) ? (v * cs.x - o * cs.y)
                                          : (o * cs.y + v * cs.x);
                }
                if constexpr (sizeof(TOUT) == 2) {
                    Y[(size_t)row * CEMB + c] = f2bf(v);
                } else {
                    Y[(size_t)row * CEMB + c] = v;
                }
            }
        }
    }
}

// ---------------------------------------------------------------------------
// Per-segment M_s[d][e] = sum_l sk[l,d]*v[l,e];  z_s[e] = sum_l sk[l,e]
// ---------------------------------------------------------------------------
__global__ __launch_bounds__(256) void segkv_kernel(
    const bf16* __restrict__ K, const bf16* __restrict__ V,
    float* __restrict__ Mseg, float* __restrict__ Zseg) {
    const int tile = blockIdx.x;
    const int b = tile >> 7, h = (tile >> 3) & 15, s = tile & 7;
    __shared__ float Ksh[16][132];
    __shared__ float Vsh[16][132];
    const int tid = threadIdx.x, tx = tid & 15, ty = tid >> 4;
    const int tbase = h * 256 + s * 32;
    const size_t bb = (size_t)b * TSEQ;

    float acc[8][8];
    float zacc[8];
#pragma unroll
    for (int i = 0; i < 8; ++i) {
        zacc[i] = 0.0f;
#pragma unroll
        for (int j = 0; j < 8; ++j) acc[i][j] = 0.0f;
    }

    for (int l0 = 0; l0 < SEGL; l0 += 16) {
        __syncthreads();
#pragma unroll
        for (int u = 0; u < 2; ++u) {
            int idx = tid + u * 256;
            int r = idx >> 5, cb = (idx & 31) << 2;
            int l = l0 + r;
            int t = tbase + (l >> 4);
            size_t addr = (bb + t) * CEMB + (size_t)((l & 15) * 128 + cb);
            float kq[4], vq[4];
            ld4(K + addr, kq);
            ld4(V + addr, vq);
#pragma unroll
            for (int q = 0; q < 4; ++q) Ksh[r][cb + q] = elup1p(kq[q]);
            *(float4*)&Vsh[r][cb] = make_float4(vq[0], vq[1], vq[2], vq[3]);
        }
        __syncthreads();
#pragma unroll
        for (int l = 0; l < 16; ++l) {
            float a[8], bv[8];
            *(float4*)&a[0] = *(const float4*)&Ksh[l][ty * 8];
            *(float4*)&a[4] = *(const float4*)&Ksh[l][ty * 8 + 4];
            *(float4*)&bv[0] = *(const float4*)&Vsh[l][tx * 8];
            *(float4*)&bv[4] = *(const float4*)&Vsh[l][tx * 8 + 4];
#pragma unroll
            for (int i = 0; i < 8; ++i)
#pragma unroll
                for (int j = 0; j < 8; ++j) acc[i][j] += a[i] * bv[j];
            if (tx == 0) {
#pragma unroll
                for (int i = 0; i < 8; ++i) zacc[i] += a[i];
            }
        }
    }
    float* Mp = Mseg + (size_t)tile * (DHEAD * DHEAD);
#pragma unroll
    for (int i = 0; i < 8; ++i) {
        int d = ty * 8 + i;
#pragma unroll
        for (int j0 = 0; j0 < 8; j0 += 4) {
            *(float4*)&Mp[d * DHEAD + tx * 8 + j0] = make_float4(
                acc[i][j0 + 0], acc[i][j0 + 1], acc[i][j0 + 2], acc[i][j0 + 3]);
        }
    }
    if (tx == 0) {
#pragma unroll
        for (int i = 0; i < 8; ++i) Zseg[tile * DHEAD + ty * 8 + i] = zacc[i];
    }
}

// ---------------------------------------------------------------------------
// In-place exclusive prefix over segments (8) for each (b,h).
// ---------------------------------------------------------------------------
__global__ __launch_bounds__(256) void prefix_kernel(
    float* __restrict__ Mseg, float* __restrict__ Zseg) {
    const int bh = blockIdx.x;
    const int tid = threadIdx.x;
    for (int e = tid; e < DHEAD * DHEAD; e += 256) {
        float acc = 0.0f;
        for (int s = 0; s < NSEG; ++s) {
            size_t idx = ((size_t)(bh * NSEG + s)) * (DHEAD * DHEAD) + e;
            float tmp = Mseg[idx];
            Mseg[idx] = acc;
            acc += tmp;
        }
    }
    if (tid < DHEAD) {
        float acc = 0.0f;
        for (int s = 0; s < NSEG; ++s) {
            size_t idx = ((size_t)(bh * NSEG + s)) * DHEAD + tid;
            float tmp = Zseg[idx];
            Zseg[idx] = acc;
            acc += tmp;
        }
    }
}

// ---------------------------------------------------------------------------
// rowsum_sq[tile*512 + l] = sum_d (elu(q[l,d])+1).  Q fp32 (post-rope).
// ---------------------------------------------------------------------------
__global__ __launch_bounds__(256) void rowsum_kernel(
    const float* __restrict__ Q, float* __restrict__ Rsum) {
    const int tid = threadIdx.x;
    const int wave = tid >> 6, lane = tid & 63;
    const int rowbase = blockIdx.x * 32 + wave * 8;
#pragma unroll
    for (int rr = 0; rr < 8; ++rr) {
        int grow = rowbase + rr;
        int tile = grow >> 9, l = grow & 511;
        int b = tile >> 7, h = (tile >> 3) & 15, s = tile & 7;
        int t = h * 256 + s * 32 + (l >> 4);
        size_t addr = ((size_t)b * TSEQ + t) * CEMB + (size_t)((l & 15) * 128 + lane * 2);
        float2 q2 = *(const float2*)(Q + addr);
        float v = elup1p(q2.x) + elup1p(q2.y);
#pragma unroll
        for (int m = 1; m < 64; m <<= 1) v += __shfl_xor(v, m, 64);
        if (lane == 0) Rsum[grow] = v;
    }
}

// ---------------------------------------------------------------------------
// A_mem: ATT[l,e] = g * (sq @ mem)[l,e] / (rowsum_sq[l]*zvec[e] + 1e-6)
// ---------------------------------------------------------------------------
__global__ __launch_bounds__(256) void amem_kernel(
    const float* __restrict__ Q, const float* __restrict__ Mpre,
    const float* __restrict__ Zpre, const float* __restrict__ Rsum,
    const float* __restrict__ beta, bf16* __restrict__ ATT) {
    const int blk = blockIdx.x;
    const int tile = blk >> 2, chunk = blk & 3;
    const int b = tile >> 7, h = (tile >> 3) & 15, s = tile & 7;
    __shared__ float As[16][132];
    __shared__ float Bs[16][132];
    const int tid = threadIdx.x, tx = tid & 15, ty = tid >> 4;
    const int tbase = h * 256 + s * 32;
    const size_t bb = (size_t)b * TSEQ;
    const int lbase = chunk * 128;
    const float* Mp = Mpre + (size_t)tile * (DHEAD * DHEAD);
    const int ar = tid >> 2, ac = (tid & 3) << 2;
    const int br = tid >> 5, bc = (tid & 31) << 2;

    float acc[8][8];
#pragma unroll
    for (int i = 0; i < 8; ++i)
#pragma unroll
        for (int j = 0; j < 8; ++j) acc[i][j] = 0.0f;

    for (int k0 = 0; k0 < DHEAD; k0 += 16) {
        int l1 = lbase + ar;
        int t1 = tbase + (l1 >> 4);
        size_t a1 = (bb + t1) * CEMB + (size_t)((l1 & 15) * 128 + k0 + ac);
        float4 av0 = *(const float4*)(Q + a1);
        int l2 = l1 + 64;
        int t2 = tbase + (l2 >> 4);
        size_t a2 = (bb + t2) * CEMB + (size_t)((l2 & 15) * 128 + k0 + ac);
        float4 av1 = *(const float4*)(Q + a2);
        float4 b0 = *(const float4*)&Mp[(k0 + br) * DHEAD + bc];
        float4 b1 = *(const float4*)&Mp[(k0 + br + 8) * DHEAD + bc];
        __syncthreads();
        As[ac + 0][ar] = elup1p(av0.x); As[ac + 1][ar] = elup1p(av0.y);
        As[ac + 2][ar] = elup1p(av0.z); As[ac + 3][ar] = elup1p(av0.w);
        As[ac + 0][ar + 64] = elup1p(av1.x); As[ac + 1][ar + 64] = elup1p(av1.y);
        As[ac + 2][ar + 64] = elup1p(av1.z); As[ac + 3][ar + 64] = elup1p(av1.w);
        *(float4*)&Bs[br][bc] = b0;
        *(float4*)&Bs[br + 8][bc] = b1;
        __syncthreads();
#pragma unroll
        for (int kk = 0; kk < 16; ++kk) {
            float a[8], bv[8];
            *(float4*)&a[0] = *(const float4*)&As[kk][ty * 8];
            *(float4*)&a[4] = *(const float4*)&As[kk][ty * 8 + 4];
            *(float4*)&bv[0] = *(const float4*)&Bs[kk][tx * 8];
            *(float4*)&bv[4] = *(const float4*)&Bs[kk][tx * 8 + 4];
#pragma unroll
            for (int i = 0; i < 8; ++i)
#pragma unroll
                for (int j = 0; j < 8; ++j) acc[i][j] += a[i] * bv[j];
        }
    }
    const float g = 1.0f / (1.0f + expf(-beta[0]));
    const float* Zp = Zpre + (size_t)tile * DHEAD;
    float zv[8];
#pragma unroll
    for (int j = 0; j < 8; ++j) zv[j] = Zp[tx * 8 + j];
#pragma unroll
    for (int i = 0; i < 8; ++i) {
        int l = lbase + ty * 8 + i;
        float rs = Rsum[(size_t)tile * SEGL + l];
        int t = tbase + (l >> 4);
        size_t rowaddr = (bb + t) * CEMB + (size_t)((l & 15) * 128);
#pragma unroll
        for (int j0 = 0; j0 < 8; j0 += 4) {
            float o[4];
#pragma unroll
            for (int q = 0; q < 4; ++q)
                o[q] = g * acc[i][j0 + q] / (rs * zv[j0 + q] + 1e-6f);
            st4(ATT + rowaddr + tx * 8 + j0, o);
        }
    }
}

// ---------------------------------------------------------------------------
// A_dot (flash-style, no mask): ATT[l,e] += (1-g) * softmax(q k^T * scale) v.
// ---------------------------------------------------------------------------
__global__ __launch_bounds__(256) void adot_kernel(
    const float* __restrict__ Q, const bf16* __restrict__ K,
    const bf16* __restrict__ V, const float* __restrict__ beta,
    bf16* __restrict__ ATT) {
    const int blk = blockIdx.x;
    const int tile = blk >> 3, chunk = blk & 7;
    const int b = tile >> 7, h = (tile >> 3) & 15, s = tile & 7;
    __shared__ float KVs[64][132];
    __shared__ float Ps[64][68];
    const int tid = threadIdx.x, tx = tid & 15, ty = tid >> 4;
    const int tbase = h * 256 + s * 32;
    const size_t bb = (size_t)b * TSEQ;
    const int lbase = chunk * 64;
    const float scale = 0.08838834764831845f;  // 1/sqrt(128)

    size_t qrow[4];
#pragma unroll
    for (int i = 0; i < 4; ++i) {
        int l = lbase + ty * 4 + i;
        int t = tbase + (l >> 4);
        qrow[i] = (bb + t) * CEMB + (size_t)((l & 15) * 128);
    }

    float Oacc[4][8];
    float mrow[4], lrow[4];
#pragma unroll
    for (int i = 0; i < 4; ++i) {
        mrow[i] = -3.4e38f;
        lrow[i] = 0.0f;
#pragma unroll
        for (int j = 0; j < 8; ++j) Oacc[i][j] = 0.0f;
    }

    for (int kc = 0; kc < 8; ++kc) {
        __syncthreads();
#pragma unroll
        for (int u = 0; u < 8; ++u) {
            int idx = tid + u * 256;
            int r = idx >> 5, cb = (idx & 31) << 2;
            int m = kc * 64 + r;
            int t = tbase + (m >> 4);
            size_t addr = (bb + t) * CEMB + (size_t)((m & 15) * 128 + cb);
            float kq[4];
            ld4(K + addr, kq);
            *(float4*)&KVs[r][cb] = make_float4(kq[0], kq[1], kq[2], kq[3]);
        }
        __syncthreads();
        float sacc[4][4];
#pragma unroll
        for (int i = 0; i < 4; ++i)
#pragma unroll
            for (int j = 0; j < 4; ++j) sacc[i][j] = 0.0f;
#pragma unroll 4
        for (int d4 = 0; d4 < DHEAD; d4 += 4) {
            float a4[4][4], b4[4][4];
#pragma unroll
            for (int i = 0; i < 4; ++i)
                *(float4*)&a4[i][0] = *(const float4*)(Q + qrow[i] + d4);
#pragma unroll
            for (int j = 0; j < 4; ++j)
                *(float4*)&b4[j][0] = *(const float4*)&KVs[tx * 4 + j][d4];
#pragma unroll
            for (int i = 0; i < 4; ++i)
#pragma unroll
                for (int j = 0; j < 4; ++j)
                    sacc[i][j] += a4[i][0] * b4[j][0] + a4[i][1] * b4[j][1] +
                                  a4[i][2] * b4[j][2] + a4[i][3] * b4[j][3];
        }
#pragma unroll
        for (int i = 0; i < 4; ++i) {
            float lm = -3.4e38f;
#pragma unroll
            for (int j = 0; j < 4; ++j) {
                sacc[i][j] *= scale;
                lm = fmaxf(lm, sacc[i][j]);
            }
#pragma unroll
            for (int m = 1; m < 16; m <<= 1) lm = fmaxf(lm, __shfl_xor(lm, m, 64));
            float mnew = fmaxf(mrow[i], lm);
            float alpha = expf(mrow[i] - mnew);
            float rsum = 0.0f;
#pragma unroll
            for (int j = 0; j < 4; ++j) {
                float p = expf(sacc[i][j] - mnew);
                Ps[ty * 4 + i][tx * 4 + j] = p;
                rsum += p;
            }
#pragma unroll
            for (int m = 1; m < 16; m <<= 1) rsum += __shfl_xor(rsum, m, 64);
            lrow[i] = lrow[i] * alpha + rsum;
            mrow[i] = mnew;
#pragma unroll
            for (int j = 0; j < 8; ++j) Oacc[i][j] *= alpha;
        }
        __syncthreads();
#pragma unroll
        for (int u = 0; u < 8; ++u) {
            int idx = tid + u * 256;
            int r = idx >> 5, cb = (idx & 31) << 2;
            int m = kc * 64 + r;
            int t = tbase + (m >> 4);
            size_t addr = (bb + t) * CEMB + (size_t)((m & 15) * 128 + cb);
            float vq[4];
            ld4(V + addr, vq);
            *(float4*)&KVs[r][cb] = make_float4(vq[0], vq[1], vq[2], vq[3]);
        }
        __syncthreads();
#pragma unroll 4
        for (int mm = 0; mm < 64; mm += 4) {
            float p4[4][4];
#pragma unroll
            for (int i = 0; i < 4; ++i)
                *(float4*)&p4[i][0] = *(const float4*)&Ps[ty * 4 + i][mm];
#pragma unroll
            for (int q = 0; q < 4; ++q) {
                float4 v0 = *(const float4*)&KVs[mm + q][tx * 8];
                float4 v1 = *(const float4*)&KVs[mm + q][tx * 8 + 4];
#pragma unroll
                for (int i = 0; i < 4; ++i) {
                    float p = p4[i][q];
                    Oacc[i][0] += p * v0.x; Oacc[i][1] += p * v0.y;
                    Oacc[i][2] += p * v0.z; Oacc[i][3] += p * v0.w;
                    Oacc[i][4] += p * v1.x; Oacc[i][5] += p * v1.y;
                    Oacc[i][6] += p * v1.z; Oacc[i][7] += p * v1.w;
                }
            }
        }
    }
    const float g = 1.0f / (1.0f + expf(-beta[0]));
    const float omg = 1.0f - g;
#pragma unroll
    for (int i = 0; i < 4; ++i) {
        float w = omg / lrow[i];
        float x0[4], x1[4];
        ld4(ATT + qrow[i] + tx * 8, x0);
        ld4(ATT + qrow[i] + tx * 8 + 4, x1);
#pragma unroll
        for (int q = 0; q < 4; ++q) {
            x0[q] += Oacc[i][q] * w;
            x1[q] += Oacc[i][q + 4] * w;
        }
        st4(ATT + qrow[i] + tx * 8, x0);
        st4(ATT + qrow[i] + tx * 8 + 4, x1);
    }
}

// ---------------------------------------------------------------------------
extern "C" void kernel_launch(void* const* d_in, const int* in_sizes, int n_in,
                              void* d_out, int out_size, void* d_ws, size_t ws_size,
                              hipStream_t stream) {
    const float* x    = (const float*)d_in[0];
    const float* Wq   = (const float*)d_in[1];
    const float* bq   = (const float*)d_in[2];
    const float* Wk   = (const float*)d_in[3];
    const float* bk   = (const float*)d_in[4];
    const float* Wv   = (const float*)d_in[5];
    const float* bv   = (const float*)d_in[6];
    const float* Wo   = (const float*)d_in[7];
    const float* bo   = (const float*)d_in[8];
    const float* beta = (const float*)d_in[9];
    float* out = (float*)d_out;

    // Workspace layout (MiB offsets):
    //   0   Kb   bf16 (64)        | 128 ATTb bf16 (64)  [= Xl during QKV gemms]
    //   64  Vb   bf16 (64)        | 192 Mseg f32 (32)   [= rope table until segkv]
    //   224 Zseg (0.25) + Rsum (1)| 226 Xh bf16 (64)
    //   290 W splits: 8 x [N][K] bf16 (8 each) -> total 354 MiB.
    char* w = (char*)d_ws;
    bf16*   Kb   = (bf16*)(w);
    bf16*   Vb   = (bf16*)(w + (64ull << 20));
    bf16*   ATTb = (bf16*)(w + (128ull << 20));
    bf16*   Xl   = ATTb;                       // alias: dead until amem writes ATT
    float*  Mseg = (float*)(w + (192ull << 20));
    float2* Rtab = (float2*)(w + (192ull << 20)); // alias: dead before segkv
    float*  Zseg = (float*)(w + (224ull << 20));
    float*  Rsum = (float*)(w + (224ull << 20) + 262144ull);
    bf16*   Xh   = (bf16*)(w + (226ull << 20));
    bf16*   Wsp  = (bf16*)(w + (290ull << 20));
    bf16* WqhT = Wsp + 0ull * 4194304;
    bf16* WqlT = Wsp + 1ull * 4194304;
    bf16* WkhT = Wsp + 2ull * 4194304;
    bf16* WklT = Wsp + 3ull * 4194304;
    bf16* WvhT = Wsp + 4ull * 4194304;
    bf16* WvlT = Wsp + 5ull * 4194304;
    bf16* WohT = Wsp + 6ull * 4194304;
    bf16* WolT = Wsp + 7ull * 4194304;

    // Q (fp32, post-rope) lives in d_out; dead before final GEMM overwrites it.
    float* Qf = out;

    rope_table_kernel<<<16384, 256, 0, stream>>>(Rtab);
    split_x_kernel<<<32768, 256, 0, stream>>>(x, Xh, Xl);
    dim3 wg(32, 32);
    split_wT_kernel<<<wg, 256, 0, stream>>>(Wq, WqhT, WqlT);
    split_wT_kernel<<<wg, 256, 0, stream>>>(Wk, WkhT, WklT);
    split_wT_kernel<<<wg, 256, 0, stream>>>(Wv, WvhT, WvlT);
    split_wT_kernel<<<wg, 256, 0, stream>>>(Wo, WohT, WolT);

    dim3 gg(CEMB / 128, BT / 128);   // (16, 128)
    // 3-phase split: Ah@Bh + Al@Bh + Ah@Bl ~= fp32 x@W
    gemm_mfma<float, true, 3><<<gg, 256, 0, stream>>>(Xh, Xl, Xh, WqhT, WqhT, WqlT, bq, Rtab, Qf);
    gemm_mfma<bf16,  true, 3><<<gg, 256, 0, stream>>>(Xh, Xl, Xh, WkhT, WkhT, WklT, bk, Rtab, Kb);
    gemm_mfma<bf16,  false,3><<<gg, 256, 0, stream>>>(Xh, Xl, Xh, WvhT, WvhT, WvlT, bv, nullptr, Vb);

    segkv_kernel<<<NTILE, 256, 0, stream>>>(Kb, Vb, Mseg, Zseg);
    prefix_kernel<<<BATCH * NHEAD, 256, 0, stream>>>(Mseg, Zseg);
    rowsum_kernel<<<(NTILE * SEGL) / 32, 256, 0, stream>>>(Qf, Rsum);
    amem_kernel<<<NTILE * 4, 256, 0, stream>>>(Qf, Mseg, Zseg, Rsum, beta, ATTb);
    adot_kernel<<<NTILE * 8, 256, 0, stream>>>(Qf, Kb, Vb, beta, ATTb);

    // 2-phase: ATT@(Woh + Wol) = ATT@Wo (ATT already bf16)
    gemm_mfma<float, false, 2><<<gg, 256, 0, stream>>>(ATTb, ATTb, nullptr, WohT, WolT, nullptr, bo, nullptr, out);
}

// Round 3
// 2521.537 us; speedup vs baseline: 3.0841x; 1.3899x over previous
//
#include <hip/hip_runtime.h>
#include <math.h>

// Problem constants
#define BATCH 4
#define TSEQ  4096
#define CEMB  2048
#define NHEAD 16
#define NSEG  8
#define SEGL  512     // L: rows per (b,h,s) tile
#define DHEAD 128
#define BT    16384   // BATCH*TSEQ
#define NTILE 512     // BATCH*NHEAD*NSEG

// tile index decode: tile = ((b*16+h)*8+s)
// row l of tile -> t = h*256 + s*32 + (l>>4); col base = (l&15)*128

typedef unsigned short bf16;
typedef __attribute__((ext_vector_type(8))) short bf16x8;  // 8 bf16 = 4 VGPRs
typedef __attribute__((ext_vector_type(8))) unsigned short u16x8;
typedef __attribute__((ext_vector_type(4))) float f32x4;

__device__ __forceinline__ float elup1p(float x) {
    return x > 0.0f ? x + 1.0f : expf(x);
}
__device__ __forceinline__ float bf2f(bf16 u) {
    return __uint_as_float(((unsigned int)u) << 16);
}
__device__ __forceinline__ bf16 f2bf(float f) {
    unsigned int x = __float_as_uint(f);
    return (bf16)((x + 0x7fffu + ((x >> 16) & 1u)) >> 16);
}
__device__ __forceinline__ void ld4(const float* p, float f[4]) {
    float4 v = *(const float4*)p;
    f[0] = v.x; f[1] = v.y; f[2] = v.z; f[3] = v.w;
}
__device__ __forceinline__ void ld4(const bf16* p, float f[4]) {
    ushort4 v = *(const ushort4*)p;
    f[0] = bf2f(v.x); f[1] = bf2f(v.y); f[2] = bf2f(v.z); f[3] = bf2f(v.w);
}
__device__ __forceinline__ void st4(float* p, const float f[4]) {
    *(float4*)p = make_float4(f[0], f[1], f[2], f[3]);
}
__device__ __forceinline__ void st4(bf16* p, const float f[4]) {
    ushort4 v;
    v.x = f2bf(f[0]); v.y = f2bf(f[1]); v.z = f2bf(f[2]); v.w = f2bf(f[3]);
    *(ushort4*)p = v;
}

// async global->LDS, 16B per lane. LDS dest is wave-uniform base + lane*16.
__device__ __forceinline__ void gload16(const void* g, void* l) {
    typedef __attribute__((address_space(1))) const char GC;
    typedef __attribute__((address_space(3))) char LC;
    GC* gp = reinterpret_cast<GC*>((unsigned long long)g);
    LC* lp = reinterpret_cast<LC*>((unsigned int)(unsigned long long)l);
    __builtin_amdgcn_global_load_lds(gp, lp, 16, 0, 0);
}

// ---------------------------------------------------------------------------
// Split fp32 -> bf16 hi/lo:  x ~= hi + lo,  |x - hi - lo| <~ 2^-18 |x|
// ---------------------------------------------------------------------------
__global__ __launch_bounds__(256) void split_x_kernel(
    const float* __restrict__ X, bf16* __restrict__ Xh, bf16* __restrict__ Xl) {
    const size_t i4 = ((size_t)blockIdx.x * 256 + threadIdx.x) * 4;
    const float4 v = *(const float4*)&X[i4];
    float f[4] = {v.x, v.y, v.z, v.w};
    ushort4 h, l;
    unsigned short* hp = &h.x;
    unsigned short* lp = &l.x;
#pragma unroll
    for (int q = 0; q < 4; ++q) {
        bf16 hi = f2bf(f[q]);
        hp[q] = hi;
        lp[q] = f2bf(f[q] - bf2f(hi));
    }
    *(ushort4*)&Xh[i4] = h;
    *(ushort4*)&Xl[i4] = l;
}

// Split + transpose W[K][N] fp32 -> WhT/WlT[N][K] bf16 (64x64 tiles).
__global__ __launch_bounds__(256) void split_wT_kernel(
    const float* __restrict__ W, bf16* __restrict__ WhT, bf16* __restrict__ WlT) {
    __shared__ float T[64][65];
    const int k0 = blockIdx.x * 64;
    const int n0 = blockIdx.y * 64;
    const int tid = threadIdx.x;
    const int tr = tid >> 4;
    const int tc4 = (tid & 15) * 4;
#pragma unroll
    for (int rr = 0; rr < 4; ++rr) {
        const int kr = rr * 16 + tr;
        const float4 v = *(const float4*)&W[(size_t)(k0 + kr) * CEMB + n0 + tc4];
        T[kr][tc4 + 0] = v.x; T[kr][tc4 + 1] = v.y;
        T[kr][tc4 + 2] = v.z; T[kr][tc4 + 3] = v.w;
    }
    __syncthreads();
#pragma unroll
    for (int rr = 0; rr < 4; ++rr) {
        const int nr = rr * 16 + tr;
        ushort4 h, l;
        unsigned short* hp = &h.x;
        unsigned short* lp = &l.x;
#pragma unroll
        for (int q = 0; q < 4; ++q) {
            float f = T[tc4 + q][nr];
            bf16 hi = f2bf(f);
            hp[q] = hi;
            lp[q] = f2bf(f - bf2f(hi));
        }
        *(ushort4*)&WhT[(size_t)(n0 + nr) * CEMB + k0 + tc4] = h;
        *(ushort4*)&WlT[(size_t)(n0 + nr) * CEMB + k0 + tc4] = l;
    }
}

// RoPE cos/sin table: tab[t*1024 + p] = (cos, sin)(t * invf[p]).
__global__ __launch_bounds__(256) void rope_table_kernel(float2* __restrict__ tab) {
    const int idx = blockIdx.x * 256 + threadIdx.x;
    const int t = idx >> 10, p = idx & 1023;
    const double kfreq = -0.0089944730195079925;  // -ln(10000)/1024
    const float invf = (float)exp((double)p * kfreq);
    const float ang = (float)t * invf;             // fp32 mult mimics reference outer()
    double sd, cd;
    sincos((double)ang, &sd, &cd);
    tab[idx] = make_float2((float)cd, (float)sd);
}

// ---------------------------------------------------------------------------
// Per-tile transpose: Vb (tile-interleaved [l][e]) -> Vt[tile][e][l] bf16.
// block = (tile, l0 chunk of 64). LDS-tiled; writes coalesced 16B.
// ---------------------------------------------------------------------------
__global__ __launch_bounds__(256) void vtrans_kernel(
    const bf16* __restrict__ V, bf16* __restrict__ Vt) {
    __shared__ bf16 Lt[128][80];   // [e][l_local], 160B row stride (16B aligned)
    const int blk = blockIdx.x;
    const int tile = blk >> 3, sub = blk & 7;
    const int l0 = sub * 64;
    const int b = tile >> 7, h = (tile >> 3) & 15, s = tile & 7;
    const int tbase = h * 256 + s * 32;
    const size_t bb = (size_t)b * TSEQ;
    const int tid = threadIdx.x;
#pragma unroll
    for (int u = 0; u < 4; ++u) {
        const int idx = tid + u * 256;           // 0..1023
        const int lr = idx >> 4;                 // 0..63
        const int e0 = (idx & 15) * 8;
        const int l = l0 + lr;
        const int t = tbase + (l >> 4);
        const size_t addr = (bb + t) * CEMB + (size_t)((l & 15) * 128 + e0);
        u16x8 v = *(const u16x8*)(V + addr);
#pragma unroll
        for (int q = 0; q < 8; ++q) Lt[e0 + q][lr] = v[q];
    }
    __syncthreads();
#pragma unroll
    for (int u = 0; u < 4; ++u) {
        const int idx = tid + u * 256;           // 0..1023
        const int e = idx >> 3;                  // 0..127
        const int lc = (idx & 7) * 8;
        u16x8 v = *(const u16x8*)&Lt[e][lc];
        *(u16x8*)(Vt + (size_t)tile * (DHEAD * SEGL) + (size_t)e * SEGL + l0 + lc) = v;
    }
}

// ---------------------------------------------------------------------------
// MFMA GEMM: Y[M,N] = sum_ph A_ph[M,K] @ B_ph[N,K]^T + bias, optional RoPE.
// ---------------------------------------------------------------------------
template <typename TOUT, bool ROPE, int NPH>
__global__ __launch_bounds__(256) void gemm_mfma(
    const bf16* __restrict__ A0, const bf16* __restrict__ A1, const bf16* __restrict__ A2,
    const bf16* __restrict__ B0, const bf16* __restrict__ B1, const bf16* __restrict__ B2,
    const float* __restrict__ bias, const float2* __restrict__ rtab,
    TOUT* __restrict__ Y) {
    __shared__ alignas(16) bf16 Asb[128 * 64];
    __shared__ alignas(16) bf16 Bsb[128 * 64];
    const int tid = threadIdx.x;
    const int lane = tid & 63;
    const int wid = __builtin_amdgcn_readfirstlane(tid >> 6);
    const int wr = wid >> 1, wc = wid & 1;
    const int n0 = blockIdx.x * 128;
    const int m0 = blockIdx.y * 128;

    f32x4 acc[4][4];
#pragma unroll
    for (int i = 0; i < 4; ++i)
#pragma unroll
        for (int j = 0; j < 4; ++j) acc[i][j] = (f32x4){0.f, 0.f, 0.f, 0.f};

    const int soct = lane >> 3;
    const int sslot = (lane & 7) ^ soct;
    const size_t arow = (size_t)(m0 + wid * 32 + soct);
    const size_t brow = (size_t)(n0 + wid * 32 + soct);

    const int frow_a0 = wr * 64 + (lane & 15);
    const int frow_b0 = wc * 64 + (lane & 15);
    const int fk = lane >> 4;

    for (int ph = 0; ph < NPH; ++ph) {
        const bf16* Ap = (ph == 0) ? A0 : ((ph == 1) ? A1 : A2);
        const bf16* Bp = (ph == 0) ? B0 : ((ph == 1) ? B1 : B2);
        const bf16* ga = Ap + arow * CEMB + sslot * 8;
        const bf16* gb = Bp + brow * CEMB + sslot * 8;
        for (int k0 = 0; k0 < CEMB; k0 += 64) {
            __syncthreads();
#pragma unroll
            for (int i = 0; i < 4; ++i)
                gload16(ga + (size_t)i * 8 * CEMB, &Asb[(wid * 32 + i * 8) * 64]);
#pragma unroll
            for (int i = 0; i < 4; ++i)
                gload16(gb + (size_t)i * 8 * CEMB, &Bsb[(wid * 32 + i * 8) * 64]);
            ga += 64; gb += 64;
            __syncthreads();
#pragma unroll
            for (int kk = 0; kk < 2; ++kk) {
                bf16x8 af[4], bfr[4];
#pragma unroll
                for (int i = 0; i < 4; ++i) {
                    const int r = frow_a0 + i * 16;
                    const int slot = (kk * 4 + fk) ^ (r & 7);
                    af[i] = *(const bf16x8*)((const char*)Asb + r * 128 + slot * 16);
                }
#pragma unroll
                for (int j = 0; j < 4; ++j) {
                    const int r = frow_b0 + j * 16;
                    const int slot = (kk * 4 + fk) ^ (r & 7);
                    bfr[j] = *(const bf16x8*)((const char*)Bsb + r * 128 + slot * 16);
                }
#pragma unroll
                for (int i = 0; i < 4; ++i)
#pragma unroll
                    for (int j = 0; j < 4; ++j)
                        acc[i][j] = __builtin_amdgcn_mfma_f32_16x16x32_bf16(
                            af[i], bfr[j], acc[i][j], 0, 0, 0);
            }
        }
    }

    const int gc0 = n0 + wc * 64 + (lane & 15);
    const int gr0 = m0 + wr * 64 + (lane >> 4) * 4;
#pragma unroll
    for (int j = 0; j < 4; ++j) {
        const int c = gc0 + j * 16;
        const float bs = bias[c];
        const int p = c >> 1;
#pragma unroll
        for (int i = 0; i < 4; ++i) {
#pragma unroll
            for (int r = 0; r < 4; ++r) {
                const int row = gr0 + i * 16 + r;
                float v = acc[i][j][r] + bs;
                if (ROPE) {
                    const float2 cs = rtab[(size_t)(row & (TSEQ - 1)) * (CEMB / 2) + p];
                    const float o = __shfl_xor(v, 1, 64);
                    v = ((lane & 1) == 0) ? (v * cs.x - o * cs.y)
                                          : (o * cs.y + v * cs.x);
                }
                if constexpr (sizeof(TOUT) == 2) {
                    Y[(size_t)row * CEMB + c] = f2bf(v);
                } else {
                    Y[(size_t)row * CEMB + c] = v;
                }
            }
        }
    }
}

// ---------------------------------------------------------------------------
// Per-segment M_s[d][e] = sum_l sk[l,d]*v[l,e];  z_s[e] = sum_l sk[l,e]
// ---------------------------------------------------------------------------
__global__ __launch_bounds__(256) void segkv_kernel(
    const bf16* __restrict__ K, const bf16* __restrict__ V,
    float* __restrict__ Mseg, float* __restrict__ Zseg) {
    const int tile = blockIdx.x;
    const int b = tile >> 7, h = (tile >> 3) & 15, s = tile & 7;
    __shared__ float Ksh[16][132];
    __shared__ float Vsh[16][132];
    const int tid = threadIdx.x, tx = tid & 15, ty = tid >> 4;
    const int tbase = h * 256 + s * 32;
    const size_t bb = (size_t)b * TSEQ;

    float acc[8][8];
    float zacc[8];
#pragma unroll
    for (int i = 0; i < 8; ++i) {
        zacc[i] = 0.0f;
#pragma unroll
        for (int j = 0; j < 8; ++j) acc[i][j] = 0.0f;
    }

    for (int l0 = 0; l0 < SEGL; l0 += 16) {
        __syncthreads();
#pragma unroll
        for (int u = 0; u < 2; ++u) {
            int idx = tid + u * 256;
            int r = idx >> 5, cb = (idx & 31) << 2;
            int l = l0 + r;
            int t = tbase + (l >> 4);
            size_t addr = (bb + t) * CEMB + (size_t)((l & 15) * 128 + cb);
            float kq[4], vq[4];
            ld4(K + addr, kq);
            ld4(V + addr, vq);
#pragma unroll
            for (int q = 0; q < 4; ++q) Ksh[r][cb + q] = elup1p(kq[q]);
            *(float4*)&Vsh[r][cb] = make_float4(vq[0], vq[1], vq[2], vq[3]);
        }
        __syncthreads();
#pragma unroll
        for (int l = 0; l < 16; ++l) {
            float a[8], bv[8];
            *(float4*)&a[0] = *(const float4*)&Ksh[l][ty * 8];
            *(float4*)&a[4] = *(const float4*)&Ksh[l][ty * 8 + 4];
            *(float4*)&bv[0] = *(const float4*)&Vsh[l][tx * 8];
            *(float4*)&bv[4] = *(const float4*)&Vsh[l][tx * 8 + 4];
#pragma unroll
            for (int i = 0; i < 8; ++i)
#pragma unroll
                for (int j = 0; j < 8; ++j) acc[i][j] += a[i] * bv[j];
            if (tx == 0) {
#pragma unroll
                for (int i = 0; i < 8; ++i) zacc[i] += a[i];
            }
        }
    }
    float* Mp = Mseg + (size_t)tile * (DHEAD * DHEAD);
#pragma unroll
    for (int i = 0; i < 8; ++i) {
        int d = ty * 8 + i;
#pragma unroll
        for (int j0 = 0; j0 < 8; j0 += 4) {
            *(float4*)&Mp[d * DHEAD + tx * 8 + j0] = make_float4(
                acc[i][j0 + 0], acc[i][j0 + 1], acc[i][j0 + 2], acc[i][j0 + 3]);
        }
    }
    if (tx == 0) {
#pragma unroll
        for (int i = 0; i < 8; ++i) Zseg[tile * DHEAD + ty * 8 + i] = zacc[i];
    }
}

// ---------------------------------------------------------------------------
// In-place exclusive prefix over segments (8) for each (b,h).
// ---------------------------------------------------------------------------
__global__ __launch_bounds__(256) void prefix_kernel(
    float* __restrict__ Mseg, float* __restrict__ Zseg) {
    const int bh = blockIdx.x;
    const int tid = threadIdx.x;
    for (int e = tid; e < DHEAD * DHEAD; e += 256) {
        float acc = 0.0f;
        for (int s = 0; s < NSEG; ++s) {
            size_t idx = ((size_t)(bh * NSEG + s)) * (DHEAD * DHEAD) + e;
            float tmp = Mseg[idx];
            Mseg[idx] = acc;
            acc += tmp;
        }
    }
    if (tid < DHEAD) {
        float acc = 0.0f;
        for (int s = 0; s < NSEG; ++s) {
            size_t idx = ((size_t)(bh * NSEG + s)) * DHEAD + tid;
            float tmp = Zseg[idx];
            Zseg[idx] = acc;
            acc += tmp;
        }
    }
}

// ---------------------------------------------------------------------------
// rowsum_sq[tile*512 + l] = sum_d (elu(q[l,d])+1).  Q fp32 (post-rope).
// ---------------------------------------------------------------------------
__global__ __launch_bounds__(256) void rowsum_kernel(
    const float* __restrict__ Q, float* __restrict__ Rsum) {
    const int tid = threadIdx.x;
    const int wave = tid >> 6, lane = tid & 63;
    const int rowbase = blockIdx.x * 32 + wave * 8;
#pragma unroll
    for (int rr = 0; rr < 8; ++rr) {
        int grow = rowbase + rr;
        int tile = grow >> 9, l = grow & 511;
        int b = tile >> 7, h = (tile >> 3) & 15, s = tile & 7;
        int t = h * 256 + s * 32 + (l >> 4);
        size_t addr = ((size_t)b * TSEQ + t) * CEMB + (size_t)((l & 15) * 128 + lane * 2);
        float2 q2 = *(const float2*)(Q + addr);
        float v = elup1p(q2.x) + elup1p(q2.y);
#pragma unroll
        for (int m = 1; m < 64; m <<= 1) v += __shfl_xor(v, m, 64);
        if (lane == 0) Rsum[grow] = v;
    }
}

// ---------------------------------------------------------------------------
// A_mem: ATT[l,e] = g * (sq @ mem)[l,e] / (rowsum_sq[l]*zvec[e] + 1e-6)
// ---------------------------------------------------------------------------
__global__ __launch_bounds__(256) void amem_kernel(
    const float* __restrict__ Q, const float* __restrict__ Mpre,
    const float* __restrict__ Zpre, const float* __restrict__ Rsum,
    const float* __restrict__ beta, bf16* __restrict__ ATT) {
    const int blk = blockIdx.x;
    const int tile = blk >> 2, chunk = blk & 3;
    const int b = tile >> 7, h = (tile >> 3) & 15, s = tile & 7;
    __shared__ float As[16][132];
    __shared__ float Bs[16][132];
    const int tid = threadIdx.x, tx = tid & 15, ty = tid >> 4;
    const int tbase = h * 256 + s * 32;
    const size_t bb = (size_t)b * TSEQ;
    const int lbase = chunk * 128;
    const float* Mp = Mpre + (size_t)tile * (DHEAD * DHEAD);
    const int ar = tid >> 2, ac = (tid & 3) << 2;
    const int br = tid >> 5, bc = (tid & 31) << 2;

    float acc[8][8];
#pragma unroll
    for (int i = 0; i < 8; ++i)
#pragma unroll
        for (int j = 0; j < 8; ++j) acc[i][j] = 0.0f;

    for (int k0 = 0; k0 < DHEAD; k0 += 16) {
        int l1 = lbase + ar;
        int t1 = tbase + (l1 >> 4);
        size_t a1 = (bb + t1) * CEMB + (size_t)((l1 & 15) * 128 + k0 + ac);
        float4 av0 = *(const float4*)(Q + a1);
        int l2 = l1 + 64;
        int t2 = tbase + (l2 >> 4);
        size_t a2 = (bb + t2) * CEMB + (size_t)((l2 & 15) * 128 + k0 + ac);
        float4 av1 = *(const float4*)(Q + a2);
        float4 b0 = *(const float4*)&Mp[(k0 + br) * DHEAD + bc];
        float4 b1 = *(const float4*)&Mp[(k0 + br + 8) * DHEAD + bc];
        __syncthreads();
        As[ac + 0][ar] = elup1p(av0.x); As[ac + 1][ar] = elup1p(av0.y);
        As[ac + 2][ar] = elup1p(av0.z); As[ac + 3][ar] = elup1p(av0.w);
        As[ac + 0][ar + 64] = elup1p(av1.x); As[ac + 1][ar + 64] = elup1p(av1.y);
        As[ac + 2][ar + 64] = elup1p(av1.z); As[ac + 3][ar + 64] = elup1p(av1.w);
        *(float4*)&Bs[br][bc] = b0;
        *(float4*)&Bs[br + 8][bc] = b1;
        __syncthreads();
#pragma unroll
        for (int kk = 0; kk < 16; ++kk) {
            float a[8], bv[8];
            *(float4*)&a[0] = *(const float4*)&As[kk][ty * 8];
            *(float4*)&a[4] = *(const float4*)&As[kk][ty * 8 + 4];
            *(float4*)&bv[0] = *(const float4*)&Bs[kk][tx * 8];
            *(float4*)&bv[4] = *(const float4*)&Bs[kk][tx * 8 + 4];
#pragma unroll
            for (int i = 0; i < 8; ++i)
#pragma unroll
                for (int j = 0; j < 8; ++j) acc[i][j] += a[i] * bv[j];
        }
    }
    const float g = 1.0f / (1.0f + expf(-beta[0]));
    const float* Zp = Zpre + (size_t)tile * DHEAD;
    float zv[8];
#pragma unroll
    for (int j = 0; j < 8; ++j) zv[j] = Zp[tx * 8 + j];
#pragma unroll
    for (int i = 0; i < 8; ++i) {
        int l = lbase + ty * 8 + i;
        float rs = Rsum[(size_t)tile * SEGL + l];
        int t = tbase + (l >> 4);
        size_t rowaddr = (bb + t) * CEMB + (size_t)((l & 15) * 128);
#pragma unroll
        for (int j0 = 0; j0 < 8; j0 += 4) {
            float o[4];
#pragma unroll
            for (int q = 0; q < 4; ++q)
                o[q] = g * acc[i][j0 + q] / (rs * zv[j0 + q] + 1e-6f);
            st4(ATT + rowaddr + tx * 8 + j0, o);
        }
    }
}

// ---------------------------------------------------------------------------
// A_dot via MFMA (flash-style): ATT[l,e] += (1-g)*softmax(q k^T * scale) v.
// Block = 4 waves x 16 q-rows = 64 rows of one tile; 8 chunks of 64 keys.
// ---------------------------------------------------------------------------
__global__ __launch_bounds__(256) void adot_mfma_kernel(
    const float* __restrict__ Q, const bf16* __restrict__ K,
    const bf16* __restrict__ Vt, const float* __restrict__ beta,
    bf16* __restrict__ ATT) {
    __shared__ alignas(16) bf16 Ks[64 * 128];    // [key][16 slots ^ (key&15)]
    __shared__ alignas(16) bf16 Vts[128 * 64];   // [e][8 slots ^ (e&7)]
    __shared__ alignas(16) bf16 Ps[4][16][64];   // per-wave P, slot ^ (row&7)
    const int tid = threadIdx.x;
    const int lane = tid & 63;
    const int w = __builtin_amdgcn_readfirstlane(tid >> 6);
    // XCD swizzle: 8 sibling q-chunks of a tile land on one XCD's L2.
    const int p = blockIdx.x;
    const int logical = (p & 7) * 512 + (p >> 3);
    const int tile = logical >> 3;
    const int lbase = (logical & 7) * 64;
    const int b = tile >> 7, h = (tile >> 3) & 15, s = tile & 7;
    const int tbase = h * 256 + s * 32;
    const size_t bb = (size_t)b * TSEQ;
    const float scale = 0.08838834764831845f;  // 1/sqrt(128)

    // Q A-fragments: 16 rows/wave, d = s4*32 + (lane>>4)*8 .. +7, hi/lo split.
    bf16x8 qh[4], ql[4];
    {
        const int lq = lbase + w * 16 + (lane & 15);
        const int t = tbase + (lq >> 4);
        const float* qp = Q + ((bb + t) * CEMB + (size_t)((lq & 15) * 128));
#pragma unroll
        for (int s4 = 0; s4 < 4; ++s4) {
            float f[8];
            *(float4*)&f[0] = *(const float4*)(qp + s4 * 32 + (lane >> 4) * 8);
            *(float4*)&f[4] = *(const float4*)(qp + s4 * 32 + (lane >> 4) * 8 + 4);
#pragma unroll
            for (int kq = 0; kq < 8; ++kq) {
                bf16 hb = f2bf(f[kq]);
                qh[s4][kq] = (short)hb;
                ql[s4][kq] = (short)f2bf(f[kq] - bf2f(hb));
            }
        }
    }

    f32x4 Oacc[8];
#pragma unroll
    for (int jb = 0; jb < 8; ++jb) Oacc[jb] = (f32x4){0.f, 0.f, 0.f, 0.f};
    float mrow[4], lrow[4];
#pragma unroll
    for (int r = 0; r < 4; ++r) { mrow[r] = -3.4e38f; lrow[r] = 0.0f; }

    for (int kc = 0; kc < 8; ++kc) {
        __syncthreads();   // prev chunk's LDS reads done
        // stage K chunk: wave w stages key rows w*16..+15 (4 x 4rows x 16slots)
#pragma unroll
        for (int i = 0; i < 4; ++i) {
            const int r = w * 16 + i * 4 + (lane >> 4);   // key row 0..63
            const int m = kc * 64 + r;
            const int srcslot = (lane & 15) ^ (r & 15);
            const bf16* g = K + ((bb + tbase + (m >> 4)) * CEMB +
                                 (size_t)((m & 15) * 128 + srcslot * 8));
            gload16(g, &Ks[(w * 16 + i * 4) * 128]);
        }
        // stage Vt chunk: wave w stages e rows w*32..+31 (4 x 8rows x 8slots)
#pragma unroll
        for (int i = 0; i < 4; ++i) {
            const int e = w * 32 + i * 8 + (lane >> 3);
            const int srcslot = (lane & 7) ^ (e & 7);
            const bf16* g = Vt + ((size_t)tile * (DHEAD * SEGL) +
                                  (size_t)e * SEGL + kc * 64 + srcslot * 8);
            gload16(g, &Vts[(w * 32 + i * 8) * 64]);
        }
        __syncthreads();   // staged (vmcnt drained by compiler)

        // QK^T: S[16 rows x 64 keys] per wave, hi+lo accumulate
        f32x4 sacc[4];
#pragma unroll
        for (int j = 0; j < 4; ++j) sacc[j] = (f32x4){0.f, 0.f, 0.f, 0.f};
#pragma unroll
        for (int s4 = 0; s4 < 4; ++s4) {
#pragma unroll
            for (int j = 0; j < 4; ++j) {
                const int rk = (lane & 15) + 16 * j;
                const int slot = (s4 * 4 + (lane >> 4)) ^ (lane & 15);
                bf16x8 kb = *(const bf16x8*)&Ks[rk * 128 + slot * 8];
                sacc[j] = __builtin_amdgcn_mfma_f32_16x16x32_bf16(qh[s4], kb, sacc[j], 0, 0, 0);
                sacc[j] = __builtin_amdgcn_mfma_f32_16x16x32_bf16(ql[s4], kb, sacc[j], 0, 0, 0);
            }
        }

        // online softmax (rows = (lane>>4)*4+r, reduce over 16-lane key groups)
        float alpha[4];
#pragma unroll
        for (int r = 0; r < 4; ++r) {
            float sv[4];
#pragma unroll
            for (int j = 0; j < 4; ++j) sv[j] = sacc[j][r] * scale;
            float lm = fmaxf(fmaxf(sv[0], sv[1]), fmaxf(sv[2], sv[3]));
#pragma unroll
            for (int m = 1; m < 16; m <<= 1) lm = fmaxf(lm, __shfl_xor(lm, m, 64));
            const float mnew = fmaxf(mrow[r], lm);
            alpha[r] = expf(mrow[r] - mnew);
            float pv[4];
            float rs = 0.0f;
#pragma unroll
            for (int j = 0; j < 4; ++j) {
                pv[j] = expf(sv[j] - mnew);
                rs += pv[j];
            }
#pragma unroll
            for (int m = 1; m < 16; m <<= 1) rs += __shfl_xor(rs, m, 64);
            lrow[r] = lrow[r] * alpha[r] + rs;
            mrow[r] = mnew;
            const int prow = (lane >> 4) * 4 + r;
#pragma unroll
            for (int j = 0; j < 4; ++j) {
                const int slot = (2 * j + ((lane & 15) >> 3)) ^ (prow & 7);
                Ps[w][prow][slot * 8 + (lane & 7)] = f2bf(pv[j]);
            }
        }
#pragma unroll
        for (int jb = 0; jb < 8; ++jb)
#pragma unroll
            for (int r = 0; r < 4; ++r) Oacc[jb][r] *= alpha[r];

        // PV: O[16 x 128] += P[16 x 64] @ V[64 x 128]
#pragma unroll
        for (int ks = 0; ks < 2; ++ks) {
            const int aslot = (ks * 4 + (lane >> 4)) ^ (lane & 7);
            bf16x8 pa = *(const bf16x8*)&Ps[w][lane & 15][aslot * 8];
#pragma unroll
            for (int jb = 0; jb < 8; ++jb) {
                const int e = (lane & 15) + 16 * jb;
                const int vslot = (ks * 4 + (lane >> 4)) ^ (lane & 7);
                bf16x8 vb = *(const bf16x8*)&Vts[e * 64 + vslot * 8];
                Oacc[jb] = __builtin_amdgcn_mfma_f32_16x16x32_bf16(pa, vb, Oacc[jb], 0, 0, 0);
            }
        }
    }

    // epilogue: RMW into ATT (scalar bf16; 16-lane groups are 32B-contiguous)
    const float g = 1.0f / (1.0f + expf(-beta[0]));
    const float omg = 1.0f - g;
#pragma unroll
    for (int r = 0; r < 4; ++r) {
        const float wc = omg / lrow[r];
        const int lq = lbase + w * 16 + (lane >> 4) * 4 + r;
        const int t = tbase + (lq >> 4);
        const size_t rowaddr = (bb + t) * CEMB + (size_t)((lq & 15) * 128);
#pragma unroll
        for (int jb = 0; jb < 8; ++jb) {
            const int e = (lane & 15) + 16 * jb;
            float v = bf2f(ATT[rowaddr + e]) + wc * Oacc[jb][r];
            ATT[rowaddr + e] = f2bf(v);
        }
    }
}

// ---------------------------------------------------------------------------
extern "C" void kernel_launch(void* const* d_in, const int* in_sizes, int n_in,
                              void* d_out, int out_size, void* d_ws, size_t ws_size,
                              hipStream_t stream) {
    const float* x    = (const float*)d_in[0];
    const float* Wq   = (const float*)d_in[1];
    const float* bq   = (const float*)d_in[2];
    const float* Wk   = (const float*)d_in[3];
    const float* bk   = (const float*)d_in[4];
    const float* Wv   = (const float*)d_in[5];
    const float* bv   = (const float*)d_in[6];
    const float* Wo   = (const float*)d_in[7];
    const float* bo   = (const float*)d_in[8];
    const float* beta = (const float*)d_in[9];
    float* out = (float*)d_out;

    // Workspace layout (MiB offsets):
    //   0   Kb   bf16 (64)        | 128 ATTb bf16 (64)  [= Xl during QKV gemms]
    //   64  Vb   bf16 (64)        | 192 Mseg f32 (32)   [= rope table until segkv]
    //   224 Zseg (0.25) + Rsum (1)| 226 Xh bf16 (64)    [= Vt after QKV gemms]
    //   290 W splits: 8 x [N][K] bf16 (8 each) -> total 354 MiB.
    char* w = (char*)d_ws;
    bf16*   Kb   = (bf16*)(w);
    bf16*   Vb   = (bf16*)(w + (64ull << 20));
    bf16*   ATTb = (bf16*)(w + (128ull << 20));
    bf16*   Xl   = ATTb;                       // alias: dead until amem writes ATT
    float*  Mseg = (float*)(w + (192ull << 20));
    float2* Rtab = (float2*)(w + (192ull << 20)); // alias: dead before segkv
    float*  Zseg = (float*)(w + (224ull << 20));
    float*  Rsum = (float*)(w + (224ull << 20) + 262144ull);
    bf16*   Xh   = (bf16*)(w + (226ull << 20));
    bf16*   Vtb  = Xh;                         // alias: Xh dead after QKV gemms
    bf16*   Wsp  = (bf16*)(w + (290ull << 20));
    bf16* WqhT = Wsp + 0ull * 4194304;
    bf16* WqlT = Wsp + 1ull * 4194304;
    bf16* WkhT = Wsp + 2ull * 4194304;
    bf16* WklT = Wsp + 3ull * 4194304;
    bf16* WvhT = Wsp + 4ull * 4194304;
    bf16* WvlT = Wsp + 5ull * 4194304;
    bf16* WohT = Wsp + 6ull * 4194304;
    bf16* WolT = Wsp + 7ull * 4194304;

    // Q (fp32, post-rope) lives in d_out; dead before final GEMM overwrites it.
    float* Qf = out;

    rope_table_kernel<<<16384, 256, 0, stream>>>(Rtab);
    split_x_kernel<<<32768, 256, 0, stream>>>(x, Xh, Xl);
    dim3 wg(32, 32);
    split_wT_kernel<<<wg, 256, 0, stream>>>(Wq, WqhT, WqlT);
    split_wT_kernel<<<wg, 256, 0, stream>>>(Wk, WkhT, WklT);
    split_wT_kernel<<<wg, 256, 0, stream>>>(Wv, WvhT, WvlT);
    split_wT_kernel<<<wg, 256, 0, stream>>>(Wo, WohT, WolT);

    dim3 gg(CEMB / 128, BT / 128);   // (16, 128)
    // 3-phase split: Ah@Bh + Al@Bh + Ah@Bl ~= fp32 x@W
    gemm_mfma<float, true, 3><<<gg, 256, 0, stream>>>(Xh, Xl, Xh, WqhT, WqhT, WqlT, bq, Rtab, Qf);
    gemm_mfma<bf16,  true, 3><<<gg, 256, 0, stream>>>(Xh, Xl, Xh, WkhT, WkhT, WklT, bk, Rtab, Kb);
    gemm_mfma<bf16,  false,3><<<gg, 256, 0, stream>>>(Xh, Xl, Xh, WvhT, WvhT, WvlT, bv, nullptr, Vb);

    // Vb -> Vt[tile][e][l] (Xh region is dead now)
    vtrans_kernel<<<NTILE * 8, 256, 0, stream>>>(Vb, Vtb);

    segkv_kernel<<<NTILE, 256, 0, stream>>>(Kb, Vb, Mseg, Zseg);
    prefix_kernel<<<BATCH * NHEAD, 256, 0, stream>>>(Mseg, Zseg);
    rowsum_kernel<<<(NTILE * SEGL) / 32, 256, 0, stream>>>(Qf, Rsum);
    amem_kernel<<<NTILE * 4, 256, 0, stream>>>(Qf, Mseg, Zseg, Rsum, beta, ATTb);
    adot_mfma_kernel<<<NTILE * 8, 256, 0, stream>>>(Qf, Kb, Vtb, beta, ATTb);

    // 2-phase: ATT@(Woh + Wol) = ATT@Wo (ATT already bf16)
    gemm_mfma<float, false, 2><<<gg, 256, 0, stream>>>(ATTb, ATTb, nullptr, WohT, WolT, nullptr, bo, nullptr, out);
}